// Round 1
// baseline (179.812 us; speedup 1.0000x reference)
//
#include <hip/hip_runtime.h>

// MoE_52037823758984: out[i] = x[i] @ W_{route[i]}^T + b_{route[i]}
// N = 2,097,152 tokens, D = 10. All f32 (route int32).
//
// Memory-bound streaming kernel: 176 MB ideal traffic -> ~28 us at 6.3 TB/s.
// Strategy:
//  - 4 rows/thread = 160 B contiguous 16B-aligned chunk = 10 float4 loads +
//    10 float4 stores; route as one int4 (perfectly coalesced).
//  - Compute BOTH experts, select with route -> all weight accesses are
//    uniform (kernel-arg pointer + constant offset) so the compiler emits
//    s_load into SGPRs / scalar cache. No LDS, no per-lane weight traffic.

#define ROWS_PER_THREAD 4
#define BLOCK 256
#define D 10

__global__ __launch_bounds__(BLOCK) void moe_kernel(
    const float* __restrict__ x,
    const float* __restrict__ W1,
    const float* __restrict__ b1,
    const float* __restrict__ W2,
    const float* __restrict__ b2,
    const int*   __restrict__ route,
    float*       __restrict__ out,
    int n)
{
    const long long tid  = (long long)blockIdx.x * BLOCK + threadIdx.x;
    const long long row0 = tid * ROWS_PER_THREAD;
    if (row0 >= n) return;

    if (row0 + ROWS_PER_THREAD <= n) {
        // ---- fast path: 4 whole rows, 16B-aligned 160B chunk ----
        const float4* __restrict__ xv = (const float4*)(x + row0 * D);
        float4*       __restrict__ ov = (float4*)(out + row0 * D);

        float v[ROWS_PER_THREAD * D];
        #pragma unroll
        for (int i = 0; i < 10; ++i) {
            float4 t = xv[i];
            v[i * 4 + 0] = t.x; v[i * 4 + 1] = t.y;
            v[i * 4 + 2] = t.z; v[i * 4 + 3] = t.w;
        }

        int4 rt = *(const int4*)(route + row0);
        int rsel[ROWS_PER_THREAD] = {rt.x, rt.y, rt.z, rt.w};

        #pragma unroll
        for (int r = 0; r < ROWS_PER_THREAD; ++r) {
            float y[D];
            #pragma unroll
            for (int j = 0; j < D; ++j) {
                float y0 = b1[j];
                float y1 = b2[j];
                #pragma unroll
                for (int k = 0; k < D; ++k) {
                    const float xk = v[r * D + k];
                    y0 = fmaf(xk, W1[j * D + k], y0);
                    y1 = fmaf(xk, W2[j * D + k], y1);
                }
                y[j] = (rsel[r] != 0) ? y1 : y0;
            }
            // x row r is fully consumed; overwrite in place
            #pragma unroll
            for (int j = 0; j < D; ++j) v[r * D + j] = y[j];
        }

        #pragma unroll
        for (int i = 0; i < 10; ++i) {
            float4 t;
            t.x = v[i * 4 + 0]; t.y = v[i * 4 + 1];
            t.z = v[i * 4 + 2]; t.w = v[i * 4 + 3];
            ov[i] = t;
        }
    } else {
        // ---- tail path (not hit for N=2097152, kept for safety) ----
        for (long long row = row0; row < n; ++row) {
            const int sel = route[row];
            for (int j = 0; j < D; ++j) {
                float y0 = b1[j];
                float y1 = b2[j];
                for (int k = 0; k < D; ++k) {
                    const float xk = x[row * D + k];
                    y0 = fmaf(xk, W1[j * D + k], y0);
                    y1 = fmaf(xk, W2[j * D + k], y1);
                }
                out[row * D + j] = sel ? y1 : y0;
            }
        }
    }
}

extern "C" void kernel_launch(void* const* d_in, const int* in_sizes, int n_in,
                              void* d_out, int out_size, void* d_ws, size_t ws_size,
                              hipStream_t stream) {
    const float* x     = (const float*)d_in[0];
    const float* W1    = (const float*)d_in[1];
    const float* b1    = (const float*)d_in[2];
    const float* W2    = (const float*)d_in[3];
    const float* b2    = (const float*)d_in[4];
    const int*   route = (const int*)d_in[5];
    float*       out   = (float*)d_out;

    const int n = in_sizes[5];  // N tokens (route length)
    const int rows_per_block = BLOCK * ROWS_PER_THREAD;  // 1024
    const int blocks = (n + rows_per_block - 1) / rows_per_block;  // 2048

    moe_kernel<<<blocks, BLOCK, 0, stream>>>(x, W1, b1, W2, b2, route, out, n);
}

// Round 2
// 165.469 us; speedup vs baseline: 1.0867x; 1.0867x over previous
//
#include <hip/hip_runtime.h>

// MoE_52037823758984: out[i] = x[i] @ W_{route[i]}^T + b_{route[i]}
// N = 2,097,152 tokens, D = 10, all f32 (route int32).
//
// R2: fully-coalesced global I/O via wave-private LDS reshuffle.
//  - Wave owns 128 rows = 320 float4s = 5 float4/lane, lane-contiguous
//    global loads/stores (1 KB = 16 lines per instruction).
//  - Lane L computes rows 2L, 2L+1 (20 floats = 5 aligned float4s in LDS).
//  - All cross-lane movement is intra-wave -> no __syncthreads; same-wave
//    DS ops are processed in order (wave_barrier() pins compiler order).
//  - Weights/bias indexed uniformly -> scalar loads; both experts computed,
//    route-selected per row.

#define BLOCK 256
#define D 10
#define ROWS_PER_WAVE 128          // 64 lanes * 2 rows
#define ROWS_PER_BLOCK 512         // 4 waves
#define F4_PER_WAVE 320            // 128 * 10 / 4

__global__ __launch_bounds__(BLOCK) void moe_kernel(
    const float* __restrict__ x,
    const float* __restrict__ W1,
    const float* __restrict__ b1,
    const float* __restrict__ W2,
    const float* __restrict__ b2,
    const int*   __restrict__ route,
    float*       __restrict__ out,
    int n)
{
    __shared__ float4 lds[(BLOCK / 64) * F4_PER_WAVE];  // 20 KB

    const int lane = threadIdx.x & 63;
    const int wave = threadIdx.x >> 6;
    const long long rowbase =
        ((long long)blockIdx.x * (BLOCK / 64) + wave) * ROWS_PER_WAVE;

    float4* __restrict__ wlds = lds + wave * F4_PER_WAVE;

    if (rowbase + ROWS_PER_WAVE <= n) {
        // ---------- stage-in: coalesced global -> LDS ----------
        const float4* __restrict__ xv = (const float4*)(x + rowbase * D);
        float4*       __restrict__ ov = (float4*)(out + rowbase * D);

        #pragma unroll
        for (int j = 0; j < 5; ++j)
            wlds[j * 64 + lane] = xv[j * 64 + lane];

        // route for this lane's two rows (coalesced int2)
        const int2 rt = ((const int2*)(route + rowbase))[lane];
        const int rsel[2] = {rt.x, rt.y};

        __builtin_amdgcn_wave_barrier();

        // ---------- gather this lane's 2 rows from LDS ----------
        float4 xr[5];
        #pragma unroll
        for (int j = 0; j < 5; ++j)
            xr[j] = wlds[lane * 5 + j];

        float xf[2 * D];
        #pragma unroll
        for (int j = 0; j < 5; ++j) {
            xf[4 * j + 0] = xr[j].x; xf[4 * j + 1] = xr[j].y;
            xf[4 * j + 2] = xr[j].z; xf[4 * j + 3] = xr[j].w;
        }

        // ---------- compute both experts, select ----------
        float yf[2 * D];
        #pragma unroll
        for (int r = 0; r < 2; ++r) {
            #pragma unroll
            for (int j = 0; j < D; ++j) {
                float y0 = b1[j];
                float y1 = b2[j];
                #pragma unroll
                for (int k = 0; k < D; ++k) {
                    const float xk = xf[r * D + k];
                    y0 = fmaf(xk, W1[j * D + k], y0);
                    y1 = fmaf(xk, W2[j * D + k], y1);
                }
                yf[r * D + j] = rsel[r] ? y1 : y0;
            }
        }

        // ---------- scatter y back to LDS (lane-private slots) ----------
        #pragma unroll
        for (int j = 0; j < 5; ++j) {
            float4 t;
            t.x = yf[4 * j + 0]; t.y = yf[4 * j + 1];
            t.z = yf[4 * j + 2]; t.w = yf[4 * j + 3];
            wlds[lane * 5 + j] = t;
        }

        __builtin_amdgcn_wave_barrier();

        // ---------- store-out: coalesced LDS -> global ----------
        #pragma unroll
        for (int j = 0; j < 5; ++j)
            ov[j * 64 + lane] = wlds[j * 64 + lane];
    } else {
        // ---------- tail (not hit for N=2097152) ----------
        for (int r = 0; r < 2; ++r) {
            const long long row = rowbase + lane * 2 + r;
            if (row < n) {
                const int sel = route[row];
                for (int j = 0; j < D; ++j) {
                    float y0 = b1[j];
                    float y1 = b2[j];
                    for (int k = 0; k < D; ++k) {
                        const float xk = x[row * D + k];
                        y0 = fmaf(xk, W1[j * D + k], y0);
                        y1 = fmaf(xk, W2[j * D + k], y1);
                    }
                    out[row * D + j] = sel ? y1 : y0;
                }
            }
        }
    }
}

extern "C" void kernel_launch(void* const* d_in, const int* in_sizes, int n_in,
                              void* d_out, int out_size, void* d_ws, size_t ws_size,
                              hipStream_t stream) {
    const float* x     = (const float*)d_in[0];
    const float* W1    = (const float*)d_in[1];
    const float* b1    = (const float*)d_in[2];
    const float* W2    = (const float*)d_in[3];
    const float* b2    = (const float*)d_in[4];
    const int*   route = (const int*)d_in[5];
    float*       out   = (float*)d_out;

    const int n = in_sizes[5];  // N tokens (route length)
    const int blocks = (n + ROWS_PER_BLOCK - 1) / ROWS_PER_BLOCK;  // 4096

    moe_kernel<<<blocks, BLOCK, 0, stream>>>(x, W1, b1, W2, b2, route, out, n);
}